// Round 4
// baseline (5503.300 us; speedup 1.0000x reference)
//
#include <hip/hip_runtime.h>
#include <stdint.h>

// ---------------------------------------------------------------------------
// EditorActorCritic: embed GEMM -> input-proj GEMM -> clustered LSTM scan ->
// actor/critic head GEMMs.  Input/output float dtype (fp32 vs bf16) detected
// at runtime from the x buffer; compute is bf16 MFMA, fp32 accumulate.
// LSTM h-exchange: counter-based release/acquire protocol, packed 2xbf16
// data words, batched polls (round 3's per-word tag retry was serialized by
// the compiler -> 13.5K cyc/step; this cuts it to ~3 batched mall rounds).
// ---------------------------------------------------------------------------

typedef short v8s __attribute__((ext_vector_type(8)));   // 8 x bf16 bits (MFMA A/B frag)
typedef float v4f __attribute__((ext_vector_type(4)));   // MFMA C/D frag

#define DEV static __device__ __forceinline__
#define DT_THRESH 4096

DEV float b2f(unsigned short h) {
    union { unsigned int u; float f; } v; v.u = ((unsigned int)h) << 16; return v.f;
}
DEV unsigned short f2b(float f) {
    union { float f; unsigned int u; } v; v.f = f;
    unsigned int u = v.u;
    return (unsigned short)((u + 0x7fffu + ((u >> 16) & 1u)) >> 16);
}
DEV float sigf(float x) {
    x = fminf(fmaxf(x, -30.f), 30.f);
    return 1.f / (1.f + __expf(-x));
}
DEV float tanh_(float x) {
    x = fminf(fmaxf(x, -15.f), 15.f);
    float e = __expf(-2.f * x);
    return (1.f - e) / (1.f + e);
}

// ---------------------------------------------------------------------------
// K0a: dones decode (robust int32/bf16/byte) + zero the dtype-flag counter.
// ---------------------------------------------------------------------------
__global__ __launch_bounds__(1024) void dones_k(const void* __restrict__ raw,
                                                int* __restrict__ dst,
                                                int* __restrict__ dt) {
    __shared__ int bad_int, bad_bf;
    int tid = threadIdx.x;
    if (tid == 0) { bad_int = 0; bad_bf = 0; dt[0] = 0; }
    __syncthreads();
    const unsigned int* w = (const unsigned int*)raw;
    int li = 0, lb = 0;
    for (int i = tid; i < 32768; i += 1024) {
        unsigned int v = w[i];
        if (v > 1u) li = 1;
        unsigned int h0 = v & 0xffffu, h1 = v >> 16;
        if ((h0 != 0u && h0 != 0x3f80u) || (h1 != 0u && h1 != 0x3f80u)) lb = 1;
    }
    if (li) atomicOr(&bad_int, 1);
    if (lb) atomicOr(&bad_bf, 1);
    __syncthreads();
    int mode = (!bad_int) ? 0 : ((!bad_bf) ? 1 : 2);
    for (int e = tid; e < 131072; e += 1024) {
        int v;
        if (mode == 0)      v = (((const int*)raw)[e] != 0);
        else if (mode == 1) v = (((const unsigned short*)raw)[e] != 0);
        else                v = (((const unsigned char*)raw)[e] != 0);
        dst[e] = v;
    }
}

// ---------------------------------------------------------------------------
// K0b: float-dtype detect (fp32 storage -> millions of large-exponent
// halfwords when read as bf16; bf16 N(0,1) -> zero).
// ---------------------------------------------------------------------------
__global__ __launch_bounds__(256) void detect_k(const unsigned short* __restrict__ xr,
                                                int* __restrict__ dt) {
    int tid = blockIdx.x * 256 + threadIdx.x;   // 16384 threads
    int cnt = 0;
    for (int i = tid; i < (1 << 24); i += 16384) {
        unsigned int e = (xr[i] >> 7) & 0xffu;
        cnt += (e >= 140u);
    }
    for (int o = 32; o; o >>= 1) cnt += __shfl_down(cnt, o);
    if ((threadIdx.x & 63) == 0 && cnt) atomicAdd(dt, cnt);
}

// ---------------------------------------------------------------------------
// K0c: x -> bf16 canonical copy.
// ---------------------------------------------------------------------------
__global__ __launch_bounds__(256) void cvt_x_k(const void* __restrict__ xr,
                                               unsigned short* __restrict__ xb,
                                               const int* __restrict__ dt) {
    int fp32i = dt[0] > DT_THRESH;
    long i4 = (long)blockIdx.x * 256 + threadIdx.x;
    if (fp32i) {
        float4 v = ((const float4*)xr)[i4];
        uint2 p;
        p.x = (unsigned int)f2b(v.x) | ((unsigned int)f2b(v.y) << 16);
        p.y = (unsigned int)f2b(v.z) | ((unsigned int)f2b(v.w) << 16);
        ((uint2*)xb)[i4] = p;
    } else {
        ((uint2*)xb)[i4] = ((const uint2*)xr)[i4];
    }
}

// ---------------------------------------------------------------------------
// K0d: transpose (and dtype-convert) weight matrices W[R][C] -> WT[C][R] bf16.
// ---------------------------------------------------------------------------
struct TransArgs {
    const void* src[9];
    unsigned short* dst[9];
    int R[9];
    int C[9];
    int prefix[10];
    int total;
};

__global__ __launch_bounds__(256) void trans_kernel(TransArgs a, const int* __restrict__ dt) {
    int fp32i = dt[0] > DT_THRESH;
    int id = blockIdx.x * 256 + threadIdx.x;
    if (id >= a.total) return;
    int m = 0;
#pragma unroll
    for (int k = 0; k < 9; k++)
        if (id >= a.prefix[k + 1]) m = k + 1;
    int e = id - a.prefix[m];
    int C = a.C[m];
    int r = e / C, c = e % C;
    unsigned short v;
    if (fp32i) v = f2b(((const float*)a.src[m])[e]);
    else       v = ((const unsigned short*)a.src[m])[e];
    a.dst[m][c * a.R[m] + r] = v;
}

// ---------------------------------------------------------------------------
// Generic bf16 GEMM (unchanged from round 3 / verified).
// ---------------------------------------------------------------------------
template <int TN, int ACT, int OM>
__global__ __launch_bounds__(256) void gemm_k(const unsigned short* __restrict__ A,
                                              const unsigned short* __restrict__ BT,
                                              const unsigned short* __restrict__ bias,
                                              void* __restrict__ Cout, long coff,
                                              const int* __restrict__ dtf,
                                              int N, int K) {
    __shared__ unsigned short As[128][40];
    __shared__ unsigned short Bs[TN][40];
    const int tid = threadIdx.x;
    const int l = tid & 63, w = tid >> 6;
    const long m0 = (long)blockIdx.x * 128;
    const int n0 = blockIdx.y * TN;
    constexpr int NRT = (TN == 128) ? 4 : 2;
    constexpr int NCT = (TN == 128) ? 4 : 1;
    int fp32o = (OM == 1) ? (dtf[0] > DT_THRESH) : 0;

    v4f acc[NRT][NCT];
    for (int i = 0; i < NRT; i++)
        for (int j = 0; j < NCT; j++) acc[i][j] = v4f{0.f, 0.f, 0.f, 0.f};

    for (int kc = 0; kc < K; kc += 32) {
        {
            int row = tid >> 1, part = tid & 1;
            const uint4* src = (const uint4*)(A + (m0 + row) * K + kc + part * 16);
            uint4 v0 = src[0], v1 = src[1];
            *(uint4*)&As[row][part * 16] = v0;
            *(uint4*)&As[row][part * 16 + 8] = v1;
        }
        if (TN == 128) {
            int row = tid >> 1, part = tid & 1;
            const uint4* src = (const uint4*)(BT + (long)(n0 + row) * K + kc + part * 16);
            uint4 v0 = src[0], v1 = src[1];
            *(uint4*)&Bs[row][part * 16] = v0;
            *(uint4*)&Bs[row][part * 16 + 8] = v1;
        } else if (tid < 32) {
            int row = tid >> 1, part = tid & 1;
            const uint4* src = (const uint4*)(BT + (long)(n0 + row) * K + kc + part * 16);
            uint4 v0 = src[0], v1 = src[1];
            *(uint4*)&Bs[row][part * 16] = v0;
            *(uint4*)&Bs[row][part * 16 + 8] = v1;
        }
        __syncthreads();

        v8s af[NRT], bf[NCT];
#pragma unroll
        for (int i = 0; i < NRT; i++) {
            int rt = (TN == 128) ? ((w >> 1) * 4 + i) : (w * 2 + i);
            af[i] = *(const v8s*)&As[rt * 16 + (l & 15)][(l >> 4) * 8];
        }
#pragma unroll
        for (int j = 0; j < NCT; j++) {
            int ct = (TN == 128) ? ((w & 1) * 4 + j) : 0;
            bf[j] = *(const v8s*)&Bs[ct * 16 + (l & 15)][(l >> 4) * 8];
        }
#pragma unroll
        for (int i = 0; i < NRT; i++)
#pragma unroll
            for (int j = 0; j < NCT; j++)
                acc[i][j] = __builtin_amdgcn_mfma_f32_16x16x32_bf16(af[i], bf[j], acc[i][j], 0, 0, 0);
        __syncthreads();
    }

#pragma unroll
    for (int j = 0; j < NCT; j++) {
        int ct = (TN == 128) ? ((w & 1) * 4 + j) : 0;
        int col = ct * 16 + (l & 15);
        float bv = b2f(bias[n0 + col]);
#pragma unroll
        for (int i = 0; i < NRT; i++) {
            int rt = (TN == 128) ? ((w >> 1) * 4 + i) : (w * 2 + i);
#pragma unroll
            for (int q = 0; q < 4; q++) {
                long row = m0 + rt * 16 + (l >> 4) * 4 + q;
                float v = acc[i][j][q] + bv;
                if (ACT == 1) v = fmaxf(v, 0.f);
                if (ACT == 2) v = tanh_(v);
                long idx = coff + row * (long)N + n0 + col;
                if (OM == 1 && fp32o) ((float*)Cout)[idx] = v;
                else ((unsigned short*)Cout)[idx] = f2b(v);
            }
        }
    }
}

// ---------------------------------------------------------------------------
// K2: LSTM scan, counter-protocol exchange.
// 16 clusters x 16 WGs (1 wave each).  Data: hbd[2 parity][cluster][16 rows]
// [128 words] (2 bf16/word).  Sync: cnt[2 parity][cluster][16 ranks], value
// = step+1 when that rank's chunk for `step` is published (release store);
// consumers poll 16 counters batched, one acquire load, then one batched
// 32-word data round.  Parity double-buffer: rank r sets cnt=t+1 only after
// consuming its parity-((t-1)&1) data, so overwrite of that parity for step
// t+1 is safe once all counters for step t are seen.
// ---------------------------------------------------------------------------
__global__ __launch_bounds__(64) void lstm_k(const unsigned short* __restrict__ xz,   // [512*256][1024]
                                             const int* __restrict__ dones,           // [512][256] decoded
                                             const void* __restrict__ h0c,
                                             const void* __restrict__ h0h,
                                             const unsigned short* __restrict__ WhT,  // [1024][256]
                                             unsigned int* __restrict__ hbd,          // [2][32768]
                                             unsigned int* __restrict__ cnt,          // [2][16][16]
                                             unsigned short* __restrict__ hs,         // [512*256][256]
                                             void* __restrict__ outv,
                                             const int* __restrict__ dtf) {
    __shared__ unsigned short Whs[64][264];  // [g*16+n][k]
    __shared__ unsigned short xzs[16][72];   // [row][g*16+n]
    __shared__ int dns[16];

    const int l = threadIdx.x;      // one wave
    const int cluster = blockIdx.x >> 4;
    const int rank = blockIdx.x & 15;
    const int bt = cluster * 16;
    const int m = l & 15;
    const int qq = l >> 4;
    const int hc = rank * 16 + m;
    const int fp32o = dtf[0] > DT_THRESH;
    const int meven = ((m & 1) == 0);

    // Wh slice -> LDS (once)
    {
        int zc = qq * 256 + rank * 16 + m;
        const unsigned short* srcp = WhT + (long)zc * 256;
#pragma unroll
        for (int k8 = 0; k8 < 32; k8++) {
            uint4 v = *(const uint4*)(srcp + k8 * 8);
            *(uint4*)&Whs[l][k8 * 8] = v;
        }
    }
    __syncthreads();

    // init: c from h0c; publish h0h chunk into parity 0; counter = 1
    float c[4], hn[4];
#pragma unroll
    for (int q = 0; q < 4; q++) {
        int row = qq * 4 + q;
        long idx = (long)(bt + row) * 256 + hc;
        c[q] = fp32o ? ((const float*)h0c)[idx] : b2f(((const unsigned short*)h0c)[idx]);
        float h0 = fp32o ? ((const float*)h0h)[idx] : b2f(((const unsigned short*)h0h)[idx]);
        unsigned short hbits = f2b(h0);
        unsigned int pr = (unsigned int)__shfl_xor((int)hbits, 1);
        if (meven) {
            unsigned int wv = (unsigned int)hbits | (pr << 16);
            __hip_atomic_store(&hbd[(size_t)cluster * 2048 + row * 128 + rank * 8 + (m >> 1)],
                               wv, __ATOMIC_RELAXED, __HIP_MEMORY_SCOPE_AGENT);
        }
        hn[q] = 0.f;
    }
    if (l == 0)
        __hip_atomic_store(&cnt[cluster * 16 + rank], 1u,
                           __ATOMIC_RELEASE, __HIP_MEMORY_SCOPE_AGENT);

    int dead = 0;

    for (int t = 0; t < 512; t++) {
        // stage dones + xz slice for this step
        if (l < 16) dns[l] = dones[t * 256 + bt + l];
        {
            int row = l >> 2, g = l & 3;
            const uint4* src = (const uint4*)(xz + ((long)(t * 256 + bt + row)) * 1024 + g * 256 + rank * 16);
            uint4 v0 = src[0], v1 = src[1];
            *(uint4*)&xzs[row][g * 16] = v0;
            *(uint4*)&xzs[row][g * 16 + 8] = v1;
        }

        // poll the 16 producer counters (batched; lanes 0-15 each own one)
        const unsigned int tv = (unsigned int)(t + 1);
        unsigned int* cb = cnt + ((size_t)(t & 1) * 16 + cluster) * 16;
        if (!dead) {
            int guard = 0;
            bool mine = (l < 16);
            while (true) {
                unsigned int v = mine ? __hip_atomic_load(&cb[l], __ATOMIC_RELAXED, __HIP_MEMORY_SCOPE_AGENT)
                                      : tv;
                if (__ballot(v == tv) == ~0ull) break;
                if (++guard > (1 << 16)) { dead = 1; break; }
            }
            // single acquire load orders the following data reads
            unsigned int va_ = __hip_atomic_load(&cb[0], __ATOMIC_ACQUIRE, __HIP_MEMORY_SCOPE_AGENT);
            if (va_ == 0xdeadbeefu) dead = 1;   // keep the load alive
        }

        // one batched data round: 32 packed words (row m, full K)
        unsigned int va[32];
        const unsigned int* db = hbd + (size_t)(t & 1) * 32768 + (size_t)cluster * 2048;
#pragma unroll
        for (int ks = 0; ks < 8; ks++)
#pragma unroll
            for (int w = 0; w < 4; w++)
                va[ks * 4 + w] = __hip_atomic_load(&db[m * 128 + ks * 16 + qq * 4 + w],
                                                   __ATOMIC_RELAXED, __HIP_MEMORY_SCOPE_AGENT);

        __syncthreads();  // dns/xzs visible

        // MFMA: 4 gate tiles, K=256
        int dnA = dns[m];
        v4f acc[4];
#pragma unroll
        for (int g = 0; g < 4; g++) acc[g] = v4f{0.f, 0.f, 0.f, 0.f};
#pragma unroll
        for (int ks = 0; ks < 8; ks++) {
            v8s a;
#pragma unroll
            for (int w = 0; w < 4; w++) {
                unsigned int word = dnA ? 0u : va[ks * 4 + w];
                a[2 * w]     = (short)(word & 0xffffu);
                a[2 * w + 1] = (short)(word >> 16);
            }
#pragma unroll
            for (int g = 0; g < 4; g++) {
                v8s b = *(const v8s*)&Whs[g * 16 + m][ks * 32 + qq * 8];
                acc[g] = __builtin_amdgcn_mfma_f32_16x16x32_bf16(a, b, acc[g], 0, 0, 0);
            }
        }

        // gates + state update + publish (packed 2/word)
        unsigned int* wb = hbd + (size_t)((t + 1) & 1) * 32768 + (size_t)cluster * 2048;
#pragma unroll
        for (int q = 0; q < 4; q++) {
            int row = qq * 4 + q;
            float zi = acc[0][q] + b2f(xzs[row][0 + m]);
            float zf = acc[1][q] + b2f(xzs[row][16 + m]);
            float zg = acc[2][q] + b2f(xzs[row][32 + m]);
            float zo = acc[3][q] + b2f(xzs[row][48 + m]);
            float cm = dns[row] ? 0.f : c[q];
            float cn = sigf(zf) * cm + sigf(zi) * tanh_(zg);
            float h = sigf(zo) * tanh_(cn);
            c[q] = cn;
            hn[q] = h;
            unsigned short hbits = f2b(h);
            unsigned int pr = (unsigned int)__shfl_xor((int)hbits, 1);
            if (meven) {
                unsigned int wv = (unsigned int)hbits | (pr << 16);
                __hip_atomic_store(&wb[row * 128 + rank * 8 + (m >> 1)],
                                   wv, __ATOMIC_RELAXED, __HIP_MEMORY_SCOPE_AGENT);
                // packed hs history write (plain store, read after kernel end)
                ((unsigned int*)hs)[((long)(t * 256 + bt + row)) * 128 + rank * 8 + (m >> 1)] = wv;
            }
        }
        if (l == 0)
            __hip_atomic_store(&cnt[((size_t)((t + 1) & 1) * 16 + cluster) * 16 + rank],
                               (unsigned int)(t + 2),
                               __ATOMIC_RELEASE, __HIP_MEMORY_SCOPE_AGENT);
    }

    // c_fin at out elems [0:65536], h_fin at [65536:131072]
#pragma unroll
    for (int q = 0; q < 4; q++) {
        int row = qq * 4 + q;
        long i1 = (long)(bt + row) * 256 + hc;
        long i2 = 65536 + i1;
        if (fp32o) {
            ((float*)outv)[i1] = c[q];
            ((float*)outv)[i2] = hn[q];
        } else {
            ((unsigned short*)outv)[i1] = f2b(c[q]);
            ((unsigned short*)outv)[i2] = f2b(hn[q]);
        }
    }
}

// ---------------------------------------------------------------------------
// value head: value[r] = v2[r] . Wc3 + bc3   (K=128, N=1)
// ---------------------------------------------------------------------------
__global__ __launch_bounds__(256) void value_k(const unsigned short* __restrict__ V2,
                                               const unsigned short* __restrict__ Wc3T,
                                               const unsigned short* __restrict__ bc3,
                                               void* __restrict__ outv,
                                               const int* __restrict__ dtf) {
    int tid = threadIdx.x;
    int l = tid & 63, w = tid >> 6;
    int fp32o = dtf[0] > DT_THRESH;
    long row = (long)blockIdx.x * 32 + w * 8 + (l >> 3);
    int sub = l & 7;
    const unsigned short* vp = V2 + row * 128 + sub * 16;
    float s = 0.f;
#pragma unroll
    for (int j = 0; j < 16; j++) s += b2f(vp[j]) * b2f(Wc3T[sub * 16 + j]);
    s += __shfl_xor(s, 1);
    s += __shfl_xor(s, 2);
    s += __shfl_xor(s, 4);
    if (sub == 0) {
        float v = s + b2f(bc3[0]);
        if (fp32o) ((float*)outv)[2228224 + row] = v;
        else ((unsigned short*)outv)[2228224 + row] = f2b(v);
    }
}

// ---------------------------------------------------------------------------
// host launcher
// ---------------------------------------------------------------------------
extern "C" void kernel_launch(void* const* d_in, const int* in_sizes, int n_in,
                              void* d_out, int out_size, void* d_ws, size_t ws_size,
                              hipStream_t stream) {
    const void* x             = d_in[0];
    const void* dones_raw     = d_in[1];
    const void* h0c           = d_in[2];
    const void* h0h           = d_in[3];
    const void* We  = d_in[4];
    const unsigned short* be  = (const unsigned short*)d_in[5];
    const void* Wi  = d_in[6];
    const void* Wh  = d_in[7];
    const unsigned short* bl  = (const unsigned short*)d_in[8];
    const void* Wa1 = d_in[9];
    const unsigned short* ba1 = (const unsigned short*)d_in[10];
    const void* Wa2 = d_in[11];
    const unsigned short* ba2 = (const unsigned short*)d_in[12];
    const void* Wa3 = d_in[13];
    const unsigned short* ba3 = (const unsigned short*)d_in[14];
    const void* Wc1 = d_in[15];
    const unsigned short* bc1 = (const unsigned short*)d_in[16];
    const void* Wc2 = d_in[17];
    const unsigned short* bc2 = (const unsigned short*)d_in[18];
    const void* Wc3 = d_in[19];
    const unsigned short* bc3 = (const unsigned short*)d_in[20];
    char* ws = (char*)d_ws;

    // workspace layout (bytes)
    unsigned short* WeT  = (unsigned short*)(ws + 0);          //   131072
    unsigned short* WiT  = (unsigned short*)(ws + 131072);     //   524288
    unsigned short* WhT  = (unsigned short*)(ws + 655360);     //   524288
    unsigned short* Wa1T = (unsigned short*)(ws + 1179648);    //    65536
    unsigned short* Wa2T = (unsigned short*)(ws + 1245184);    //    32768
    unsigned short* Wa3T = (unsigned short*)(ws + 1277952);    //     4096
    unsigned short* Wc1T = (unsigned short*)(ws + 1282048);    //    65536
    unsigned short* Wc2T = (unsigned short*)(ws + 1347584);    //    32768
    unsigned short* Wc3T = (unsigned short*)(ws + 1380352);    //      256
    int*            DT   = (int*)(ws + 1380608);               //       64
    unsigned int*   HBD  = (unsigned int*)(ws + 1380672);      //   262144 (2x32768 words)
    unsigned int*   CNT  = (unsigned int*)(ws + 1642816);      //     2048 (2x16x16 words)
    int*            DN   = (int*)(ws + 1904960);               //   524288
    unsigned short* XB   = (unsigned short*)(ws + 2429248);    // 67108864
    unsigned short* E    = (unsigned short*)(ws + 69538112);   // 67108864
    unsigned short* XZ   = (unsigned short*)(ws + 136646976);  // 268435456
    unsigned short* HS   = (unsigned short*)(ws + 405082432);  // 67108864 -> ends 472191296
    unsigned short* H1   = XB;                                  // alias (XB dead post-E)
    unsigned short* H2   = XB + 16777216;

    TransArgs ta;
    {
        const void* srcs[9] = {We, Wi, Wh, Wa1, Wa2, Wa3, Wc1, Wc2, Wc3};
        unsigned short* dsts[9] = {WeT, WiT, WhT, Wa1T, Wa2T, Wa3T, Wc1T, Wc2T, Wc3T};
        int Rs[9] = {256, 256, 256, 256, 128, 128, 256, 128, 128};
        int Cs[9] = {256, 1024, 1024, 128, 128, 16, 128, 128, 1};
        int p = 0;
        for (int i = 0; i < 9; i++) {
            ta.src[i] = srcs[i];
            ta.dst[i] = dsts[i];
            ta.R[i] = Rs[i];
            ta.C[i] = Cs[i];
            ta.prefix[i] = p;
            p += Rs[i] * Cs[i];
        }
        ta.prefix[9] = p;
        ta.total = p;  // 690304
    }

    dones_k<<<1, 1024, 0, stream>>>(dones_raw, DN, DT);
    detect_k<<<64, 256, 0, stream>>>((const unsigned short*)x, DT);
    cvt_x_k<<<32768, 256, 0, stream>>>(x, XB, DT);
    trans_kernel<<<2697, 256, 0, stream>>>(ta, DT);

    // E = relu(x @ We + be)            [131072 x 256]
    gemm_k<128, 1, 0><<<dim3(1024, 2), 256, 0, stream>>>(XB, WeT, be, E, 0, nullptr, 256, 256);
    // XZ = E @ Wi + b_lstm             [131072 x 1024]
    gemm_k<128, 0, 0><<<dim3(1024, 8), 256, 0, stream>>>(E, WiT, bl, XZ, 0, nullptr, 1024, 256);
    // LSTM scan -> HS, c_fin, h_fin
    lstm_k<<<256, 64, 0, stream>>>(XZ, DN, h0c, h0h, WhT, HBD, CNT, HS, d_out, DT);
    // actor head
    gemm_k<128, 2, 0><<<dim3(1024, 1), 256, 0, stream>>>(HS, Wa1T, ba1, H1, 0, nullptr, 128, 256);
    gemm_k<128, 2, 0><<<dim3(1024, 1), 256, 0, stream>>>(H1, Wa2T, ba2, H2, 0, nullptr, 128, 128);
    gemm_k<16, 0, 1><<<dim3(1024, 1), 256, 0, stream>>>(H2, Wa3T, ba3, d_out, 131072, DT, 16, 128);
    // critic head
    gemm_k<128, 2, 0><<<dim3(1024, 1), 256, 0, stream>>>(HS, Wc1T, bc1, H1, 0, nullptr, 128, 256);
    gemm_k<128, 2, 0><<<dim3(1024, 1), 256, 0, stream>>>(H1, Wc2T, bc2, H2, 0, nullptr, 128, 128);
    value_k<<<4096, 256, 0, stream>>>(H2, Wc3T, bc3, d_out, DT);
}

// Round 5
// 4347.648 us; speedup vs baseline: 1.2658x; 1.2658x over previous
//
#include <hip/hip_runtime.h>
#include <stdint.h>

// ---------------------------------------------------------------------------
// EditorActorCritic: embed GEMM -> input-proj GEMM -> clustered LSTM scan ->
// actor/critic head GEMMs.  Input/output float dtype (fp32 vs bf16) detected
// at runtime; compute is bf16 MFMA, fp32 accumulate.
// LSTM h-exchange: round-3 all-RELAXED tag-in-word protocol ({tag:16,h:16}
// per 4B word, parity double-buffer) -- release/acquire (round 4) regressed
// 65% via per-step cache-maintenance.  Retry loop restructured to batched
// full sweeps (round 3's per-word conditional reloads serialized ~64 mall
// round-trips/step -> 13.5K cyc).
// ---------------------------------------------------------------------------

typedef short v8s __attribute__((ext_vector_type(8)));   // 8 x bf16 bits (MFMA A/B frag)
typedef float v4f __attribute__((ext_vector_type(4)));   // MFMA C/D frag

#define DEV static __device__ __forceinline__
#define DT_THRESH 4096

DEV float b2f(unsigned short h) {
    union { unsigned int u; float f; } v; v.u = ((unsigned int)h) << 16; return v.f;
}
DEV unsigned short f2b(float f) {
    union { float f; unsigned int u; } v; v.f = f;
    unsigned int u = v.u;
    return (unsigned short)((u + 0x7fffu + ((u >> 16) & 1u)) >> 16);
}
DEV float sigf(float x) {
    x = fminf(fmaxf(x, -30.f), 30.f);
    return 1.f / (1.f + __expf(-x));
}
DEV float tanh_(float x) {
    x = fminf(fmaxf(x, -15.f), 15.f);
    float e = __expf(-2.f * x);
    return (1.f - e) / (1.f + e);
}

// ---------------------------------------------------------------------------
// K0a: dones decode (robust int32/bf16/byte) + zero the dtype-flag counter.
// ---------------------------------------------------------------------------
__global__ __launch_bounds__(1024) void dones_k(const void* __restrict__ raw,
                                                int* __restrict__ dst,
                                                int* __restrict__ dt) {
    __shared__ int bad_int, bad_bf;
    int tid = threadIdx.x;
    if (tid == 0) { bad_int = 0; bad_bf = 0; dt[0] = 0; }
    __syncthreads();
    const unsigned int* w = (const unsigned int*)raw;
    int li = 0, lb = 0;
    for (int i = tid; i < 32768; i += 1024) {
        unsigned int v = w[i];
        if (v > 1u) li = 1;
        unsigned int h0 = v & 0xffffu, h1 = v >> 16;
        if ((h0 != 0u && h0 != 0x3f80u) || (h1 != 0u && h1 != 0x3f80u)) lb = 1;
    }
    if (li) atomicOr(&bad_int, 1);
    if (lb) atomicOr(&bad_bf, 1);
    __syncthreads();
    int mode = (!bad_int) ? 0 : ((!bad_bf) ? 1 : 2);
    for (int e = tid; e < 131072; e += 1024) {
        int v;
        if (mode == 0)      v = (((const int*)raw)[e] != 0);
        else if (mode == 1) v = (((const unsigned short*)raw)[e] != 0);
        else                v = (((const unsigned char*)raw)[e] != 0);
        dst[e] = v;
    }
}

// ---------------------------------------------------------------------------
// K0b: float-dtype detect (fp32 storage -> millions of large-exponent
// halfwords when read as bf16; bf16 N(0,1) -> zero).
// ---------------------------------------------------------------------------
__global__ __launch_bounds__(256) void detect_k(const unsigned short* __restrict__ xr,
                                                int* __restrict__ dt) {
    int tid = blockIdx.x * 256 + threadIdx.x;   // 16384 threads
    int cnt = 0;
    for (int i = tid; i < (1 << 24); i += 16384) {
        unsigned int e = (xr[i] >> 7) & 0xffu;
        cnt += (e >= 140u);
    }
    for (int o = 32; o; o >>= 1) cnt += __shfl_down(cnt, o);
    if ((threadIdx.x & 63) == 0 && cnt) atomicAdd(dt, cnt);
}

// ---------------------------------------------------------------------------
// K0c: x -> bf16 canonical copy.
// ---------------------------------------------------------------------------
__global__ __launch_bounds__(256) void cvt_x_k(const void* __restrict__ xr,
                                               unsigned short* __restrict__ xb,
                                               const int* __restrict__ dt) {
    int fp32i = dt[0] > DT_THRESH;
    long i4 = (long)blockIdx.x * 256 + threadIdx.x;
    if (fp32i) {
        float4 v = ((const float4*)xr)[i4];
        uint2 p;
        p.x = (unsigned int)f2b(v.x) | ((unsigned int)f2b(v.y) << 16);
        p.y = (unsigned int)f2b(v.z) | ((unsigned int)f2b(v.w) << 16);
        ((uint2*)xb)[i4] = p;
    } else {
        ((uint2*)xb)[i4] = ((const uint2*)xr)[i4];
    }
}

// ---------------------------------------------------------------------------
// K0d: transpose (and dtype-convert) weight matrices W[R][C] -> WT[C][R] bf16.
// ---------------------------------------------------------------------------
struct TransArgs {
    const void* src[9];
    unsigned short* dst[9];
    int R[9];
    int C[9];
    int prefix[10];
    int total;
};

__global__ __launch_bounds__(256) void trans_kernel(TransArgs a, const int* __restrict__ dt) {
    int fp32i = dt[0] > DT_THRESH;
    int id = blockIdx.x * 256 + threadIdx.x;
    if (id >= a.total) return;
    int m = 0;
#pragma unroll
    for (int k = 0; k < 9; k++)
        if (id >= a.prefix[k + 1]) m = k + 1;
    int e = id - a.prefix[m];
    int C = a.C[m];
    int r = e / C, c = e % C;
    unsigned short v;
    if (fp32i) v = f2b(((const float*)a.src[m])[e]);
    else       v = ((const unsigned short*)a.src[m])[e];
    a.dst[m][c * a.R[m] + r] = v;
}

// ---------------------------------------------------------------------------
// Generic bf16 GEMM (verified since round 3).
// ---------------------------------------------------------------------------
template <int TN, int ACT, int OM>
__global__ __launch_bounds__(256) void gemm_k(const unsigned short* __restrict__ A,
                                              const unsigned short* __restrict__ BT,
                                              const unsigned short* __restrict__ bias,
                                              void* __restrict__ Cout, long coff,
                                              const int* __restrict__ dtf,
                                              int N, int K) {
    __shared__ unsigned short As[128][40];
    __shared__ unsigned short Bs[TN][40];
    const int tid = threadIdx.x;
    const int l = tid & 63, w = tid >> 6;
    const long m0 = (long)blockIdx.x * 128;
    const int n0 = blockIdx.y * TN;
    constexpr int NRT = (TN == 128) ? 4 : 2;
    constexpr int NCT = (TN == 128) ? 4 : 1;
    int fp32o = (OM == 1) ? (dtf[0] > DT_THRESH) : 0;

    v4f acc[NRT][NCT];
    for (int i = 0; i < NRT; i++)
        for (int j = 0; j < NCT; j++) acc[i][j] = v4f{0.f, 0.f, 0.f, 0.f};

    for (int kc = 0; kc < K; kc += 32) {
        {
            int row = tid >> 1, part = tid & 1;
            const uint4* src = (const uint4*)(A + (m0 + row) * K + kc + part * 16);
            uint4 v0 = src[0], v1 = src[1];
            *(uint4*)&As[row][part * 16] = v0;
            *(uint4*)&As[row][part * 16 + 8] = v1;
        }
        if (TN == 128) {
            int row = tid >> 1, part = tid & 1;
            const uint4* src = (const uint4*)(BT + (long)(n0 + row) * K + kc + part * 16);
            uint4 v0 = src[0], v1 = src[1];
            *(uint4*)&Bs[row][part * 16] = v0;
            *(uint4*)&Bs[row][part * 16 + 8] = v1;
        } else if (tid < 32) {
            int row = tid >> 1, part = tid & 1;
            const uint4* src = (const uint4*)(BT + (long)(n0 + row) * K + kc + part * 16);
            uint4 v0 = src[0], v1 = src[1];
            *(uint4*)&Bs[row][part * 16] = v0;
            *(uint4*)&Bs[row][part * 16 + 8] = v1;
        }
        __syncthreads();

        v8s af[NRT], bf[NCT];
#pragma unroll
        for (int i = 0; i < NRT; i++) {
            int rt = (TN == 128) ? ((w >> 1) * 4 + i) : (w * 2 + i);
            af[i] = *(const v8s*)&As[rt * 16 + (l & 15)][(l >> 4) * 8];
        }
#pragma unroll
        for (int j = 0; j < NCT; j++) {
            int ct = (TN == 128) ? ((w & 1) * 4 + j) : 0;
            bf[j] = *(const v8s*)&Bs[ct * 16 + (l & 15)][(l >> 4) * 8];
        }
#pragma unroll
        for (int i = 0; i < NRT; i++)
#pragma unroll
            for (int j = 0; j < NCT; j++)
                acc[i][j] = __builtin_amdgcn_mfma_f32_16x16x32_bf16(af[i], bf[j], acc[i][j], 0, 0, 0);
        __syncthreads();
    }

#pragma unroll
    for (int j = 0; j < NCT; j++) {
        int ct = (TN == 128) ? ((w & 1) * 4 + j) : 0;
        int col = ct * 16 + (l & 15);
        float bv = b2f(bias[n0 + col]);
#pragma unroll
        for (int i = 0; i < NRT; i++) {
            int rt = (TN == 128) ? ((w >> 1) * 4 + i) : (w * 2 + i);
#pragma unroll
            for (int q = 0; q < 4; q++) {
                long row = m0 + rt * 16 + (l >> 4) * 4 + q;
                float v = acc[i][j][q] + bv;
                if (ACT == 1) v = fmaxf(v, 0.f);
                if (ACT == 2) v = tanh_(v);
                long idx = coff + row * (long)N + n0 + col;
                if (OM == 1 && fp32o) ((float*)Cout)[idx] = v;
                else ((unsigned short*)Cout)[idx] = f2b(v);
            }
        }
    }
}

// ---------------------------------------------------------------------------
// K2: LSTM scan.  16 clusters x 16 WGs (1 wave).  Exchange: tag-in-word
// {step_tag:16, h_bf16:16}, RELAXED agent atomics only, parity double-buffer.
// Poll = batched full sweeps: 64 unconditional loads in flight, one waitcnt,
// ballot check, repeat.  No acquire/release anywhere (round-4 lesson).
// ---------------------------------------------------------------------------
#define HB_WORDS 65536

__global__ __launch_bounds__(64) void lstm_k(const unsigned short* __restrict__ xz,   // [512*256][1024]
                                             const int* __restrict__ dones,           // [512][256] decoded
                                             const void* __restrict__ h0c,
                                             const void* __restrict__ h0h,
                                             const unsigned short* __restrict__ WhT,  // [1024][256]
                                             unsigned int* __restrict__ hb,           // [2][65536]
                                             unsigned short* __restrict__ hs,         // [512*256][256] (bf16)
                                             void* __restrict__ outv,
                                             const int* __restrict__ dtf) {
    __shared__ unsigned short Whs[64][264];  // [g*16+n][k]
    __shared__ unsigned short xzs[16][72];   // [row][g*16+n]
    __shared__ int dns[16];

    const int l = threadIdx.x;      // one wave
    const int cluster = blockIdx.x >> 4;
    const int rank = blockIdx.x & 15;
    const int bt = cluster * 16;
    const int m = l & 15;
    const int qq = l >> 4;
    const int hc = rank * 16 + m;
    const int fp32o = dtf[0] > DT_THRESH;
    const int meven = ((m & 1) == 0);

    // Wh slice -> LDS (once)
    {
        int zc = qq * 256 + rank * 16 + m;
        const unsigned short* srcp = WhT + (long)zc * 256;
#pragma unroll
        for (int k8 = 0; k8 < 32; k8++) {
            uint4 v = *(const uint4*)(srcp + k8 * 8);
            *(uint4*)&Whs[l][k8 * 8] = v;
        }
    }
    __syncthreads();

    // init: c from h0c; publish h0h into parity-0 words with tag 0
    float c[4], hn[4];
#pragma unroll
    for (int q = 0; q < 4; q++) {
        int row = qq * 4 + q;
        long idx = (long)(bt + row) * 256 + hc;
        c[q] = fp32o ? ((const float*)h0c)[idx] : b2f(((const unsigned short*)h0c)[idx]);
        float h0 = fp32o ? ((const float*)h0h)[idx] : b2f(((const unsigned short*)h0h)[idx]);
        unsigned short hbits = f2b(h0);
        __hip_atomic_store(&hb[(size_t)cluster * 4096 + row * 256 + hc],
                           (unsigned int)hbits,   // tag 0 in high bits
                           __ATOMIC_RELAXED, __HIP_MEMORY_SCOPE_AGENT);
        hn[q] = 0.f;
    }

    int dead = 0;
    unsigned int va[64];

    for (int t = 0; t < 512; t++) {
        const unsigned int tag = (unsigned int)t;
        unsigned int* rb = hb + (size_t)(t & 1) * HB_WORDS + (size_t)cluster * 4096;

        // stage dones + xz slice for this step (loads overlap the poll sweeps)
        if (l < 16) dns[l] = dones[t * 256 + bt + l];
        {
            int row = l >> 2, g = l & 3;
            const uint4* src = (const uint4*)(xz + ((long)(t * 256 + bt + row)) * 1024 + g * 256 + rank * 16);
            uint4 v0 = src[0], v1 = src[1];
            *(uint4*)&xzs[row][g * 16] = v0;
            *(uint4*)&xzs[row][g * 16 + 8] = v1;
        }

        // batched poll sweeps: reload ALL 64 words unconditionally each sweep
        // (lane needs A row m, k = ks*32 + qq*8 + j)
        if (!dead) {
            int guard = 0;
            while (true) {
#pragma unroll
                for (int ks = 0; ks < 8; ks++)
#pragma unroll
                    for (int j = 0; j < 8; j++)
                        va[ks * 8 + j] = __hip_atomic_load(&rb[m * 256 + ks * 32 + qq * 8 + j],
                                                           __ATOMIC_RELAXED, __HIP_MEMORY_SCOPE_AGENT);
                unsigned int okl = 1u;
#pragma unroll
                for (int i = 0; i < 64; i++) okl &= ((va[i] >> 16) == tag) ? 1u : 0u;
                if (__ballot(okl != 0u) == ~0ull) break;
                if (++guard > (1 << 13)) { dead = 1; break; }   // bail, visible as huge dur
            }
        }
        __syncthreads();  // dns/xzs visible

        // MFMA: 4 gate tiles, K=256
        int dnA = dns[m];
        v4f acc[4];
#pragma unroll
        for (int g = 0; g < 4; g++) acc[g] = v4f{0.f, 0.f, 0.f, 0.f};
#pragma unroll
        for (int ks = 0; ks < 8; ks++) {
            v8s a;
#pragma unroll
            for (int j = 0; j < 8; j++)
                a[j] = dnA ? (short)0 : (short)(va[ks * 8 + j] & 0xffffu);
#pragma unroll
            for (int g = 0; g < 4; g++) {
                v8s b = *(const v8s*)&Whs[g * 16 + m][ks * 32 + qq * 8];
                acc[g] = __builtin_amdgcn_mfma_f32_16x16x32_bf16(a, b, acc[g], 0, 0, 0);
            }
        }

        // gates + state update + publish {t+1, h} + packed hs history
        unsigned int* wb = hb + (size_t)((t + 1) & 1) * HB_WORDS + (size_t)cluster * 4096;
#pragma unroll
        for (int q = 0; q < 4; q++) {
            int row = qq * 4 + q;
            float zi = acc[0][q] + b2f(xzs[row][0 + m]);
            float zf = acc[1][q] + b2f(xzs[row][16 + m]);
            float zg = acc[2][q] + b2f(xzs[row][32 + m]);
            float zo = acc[3][q] + b2f(xzs[row][48 + m]);
            float cm = dns[row] ? 0.f : c[q];
            float cn = sigf(zf) * cm + sigf(zi) * tanh_(zg);
            float h = sigf(zo) * tanh_(cn);
            c[q] = cn;
            hn[q] = h;
            unsigned short hbits = f2b(h);
            __hip_atomic_store(&wb[row * 256 + hc],
                               (((unsigned int)(t + 1)) << 16) | (unsigned int)hbits,
                               __ATOMIC_RELAXED, __HIP_MEMORY_SCOPE_AGENT);
            unsigned int pr = (unsigned int)__shfl_xor((int)hbits, 1);
            if (meven) {
                unsigned int wv = (unsigned int)hbits | (pr << 16);
                ((unsigned int*)hs)[((long)(t * 256 + bt + row)) * 128 + rank * 8 + (m >> 1)] = wv;
            }
        }
    }

    // c_fin at out elems [0:65536], h_fin at [65536:131072]
#pragma unroll
    for (int q = 0; q < 4; q++) {
        int row = qq * 4 + q;
        long i1 = (long)(bt + row) * 256 + hc;
        long i2 = 65536 + i1;
        if (fp32o) {
            ((float*)outv)[i1] = c[q];
            ((float*)outv)[i2] = hn[q];
        } else {
            ((unsigned short*)outv)[i1] = f2b(c[q]);
            ((unsigned short*)outv)[i2] = f2b(hn[q]);
        }
    }
}

// ---------------------------------------------------------------------------
// value head: value[r] = v2[r] . Wc3 + bc3   (K=128, N=1)
// ---------------------------------------------------------------------------
__global__ __launch_bounds__(256) void value_k(const unsigned short* __restrict__ V2,
                                               const unsigned short* __restrict__ Wc3T,
                                               const unsigned short* __restrict__ bc3,
                                               void* __restrict__ outv,
                                               const int* __restrict__ dtf) {
    int tid = threadIdx.x;
    int l = tid & 63, w = tid >> 6;
    int fp32o = dtf[0] > DT_THRESH;
    long row = (long)blockIdx.x * 32 + w * 8 + (l >> 3);
    int sub = l & 7;
    const unsigned short* vp = V2 + row * 128 + sub * 16;
    float s = 0.f;
#pragma unroll
    for (int j = 0; j < 16; j++) s += b2f(vp[j]) * b2f(Wc3T[sub * 16 + j]);
    s += __shfl_xor(s, 1);
    s += __shfl_xor(s, 2);
    s += __shfl_xor(s, 4);
    if (sub == 0) {
        float v = s + b2f(bc3[0]);
        if (fp32o) ((float*)outv)[2228224 + row] = v;
        else ((unsigned short*)outv)[2228224 + row] = f2b(v);
    }
}

// ---------------------------------------------------------------------------
// host launcher
// ---------------------------------------------------------------------------
extern "C" void kernel_launch(void* const* d_in, const int* in_sizes, int n_in,
                              void* d_out, int out_size, void* d_ws, size_t ws_size,
                              hipStream_t stream) {
    const void* x             = d_in[0];
    const void* dones_raw     = d_in[1];
    const void* h0c           = d_in[2];
    const void* h0h           = d_in[3];
    const void* We  = d_in[4];
    const unsigned short* be  = (const unsigned short*)d_in[5];
    const void* Wi  = d_in[6];
    const void* Wh  = d_in[7];
    const unsigned short* bl  = (const unsigned short*)d_in[8];
    const void* Wa1 = d_in[9];
    const unsigned short* ba1 = (const unsigned short*)d_in[10];
    const void* Wa2 = d_in[11];
    const unsigned short* ba2 = (const unsigned short*)d_in[12];
    const void* Wa3 = d_in[13];
    const unsigned short* ba3 = (const unsigned short*)d_in[14];
    const void* Wc1 = d_in[15];
    const unsigned short* bc1 = (const unsigned short*)d_in[16];
    const void* Wc2 = d_in[17];
    const unsigned short* bc2 = (const unsigned short*)d_in[18];
    const void* Wc3 = d_in[19];
    const unsigned short* bc3 = (const unsigned short*)d_in[20];
    char* ws = (char*)d_ws;

    // workspace layout (bytes)
    unsigned short* WeT  = (unsigned short*)(ws + 0);          //   131072
    unsigned short* WiT  = (unsigned short*)(ws + 131072);     //   524288
    unsigned short* WhT  = (unsigned short*)(ws + 655360);     //   524288
    unsigned short* Wa1T = (unsigned short*)(ws + 1179648);    //    65536
    unsigned short* Wa2T = (unsigned short*)(ws + 1245184);    //    32768
    unsigned short* Wa3T = (unsigned short*)(ws + 1277952);    //     4096
    unsigned short* Wc1T = (unsigned short*)(ws + 1282048);    //    65536
    unsigned short* Wc2T = (unsigned short*)(ws + 1347584);    //    32768
    unsigned short* Wc3T = (unsigned short*)(ws + 1380352);    //      256
    int*            DT   = (int*)(ws + 1380608);               //       64
    unsigned int*   HB   = (unsigned int*)(ws + 1380672);      //   524288 (2x65536 words)
    int*            DN   = (int*)(ws + 1904960);               //   524288
    unsigned short* XB   = (unsigned short*)(ws + 2429248);    // 67108864
    unsigned short* E    = (unsigned short*)(ws + 69538112);   // 67108864
    unsigned short* XZ   = (unsigned short*)(ws + 136646976);  // 268435456
    unsigned short* HS   = (unsigned short*)(ws + 405082432);  // 67108864 -> ends 472191296
    unsigned short* H1   = XB;                                  // alias (XB dead post-E)
    unsigned short* H2   = XB + 16777216;

    TransArgs ta;
    {
        const void* srcs[9] = {We, Wi, Wh, Wa1, Wa2, Wa3, Wc1, Wc2, Wc3};
        unsigned short* dsts[9] = {WeT, WiT, WhT, Wa1T, Wa2T, Wa3T, Wc1T, Wc2T, Wc3T};
        int Rs[9] = {256, 256, 256, 256, 128, 128, 256, 128, 128};
        int Cs[9] = {256, 1024, 1024, 128, 128, 16, 128, 128, 1};
        int p = 0;
        for (int i = 0; i < 9; i++) {
            ta.src[i] = srcs[i];
            ta.dst[i] = dsts[i];
            ta.R[i] = Rs[i];
            ta.C[i] = Cs[i];
            ta.prefix[i] = p;
            p += Rs[i] * Cs[i];
        }
        ta.prefix[9] = p;
        ta.total = p;  // 690304
    }

    dones_k<<<1, 1024, 0, stream>>>(dones_raw, DN, DT);
    detect_k<<<64, 256, 0, stream>>>((const unsigned short*)x, DT);
    cvt_x_k<<<32768, 256, 0, stream>>>(x, XB, DT);
    trans_kernel<<<2697, 256, 0, stream>>>(ta, DT);

    // E = relu(x @ We + be)            [131072 x 256]
    gemm_k<128, 1, 0><<<dim3(1024, 2), 256, 0, stream>>>(XB, WeT, be, E, 0, nullptr, 256, 256);
    // XZ = E @ Wi + b_lstm             [131072 x 1024]
    gemm_k<128, 0, 0><<<dim3(1024, 8), 256, 0, stream>>>(E, WiT, bl, XZ, 0, nullptr, 1024, 256);
    // LSTM scan -> HS, c_fin, h_fin
    lstm_k<<<256, 64, 0, stream>>>(XZ, DN, h0c, h0h, WhT, HB, HS, d_out, DT);
    // actor head
    gemm_k<128, 2, 0><<<dim3(1024, 1), 256, 0, stream>>>(HS, Wa1T, ba1, H1, 0, nullptr, 128, 256);
    gemm_k<128, 2, 0><<<dim3(1024, 1), 256, 0, stream>>>(H1, Wa2T, ba2, H2, 0, nullptr, 128, 128);
    gemm_k<16, 0, 1><<<dim3(1024, 1), 256, 0, stream>>>(H2, Wa3T, ba3, d_out, 131072, DT, 16, 128);
    // critic head
    gemm_k<128, 2, 0><<<dim3(1024, 1), 256, 0, stream>>>(HS, Wc1T, bc1, H1, 0, nullptr, 128, 256);
    gemm_k<128, 2, 0><<<dim3(1024, 1), 256, 0, stream>>>(H1, Wc2T, bc2, H2, 0, nullptr, 128, 128);
    value_k<<<4096, 256, 0, stream>>>(H2, Wc3T, bc3, d_out, DT);
}

// Round 6
// 2838.277 us; speedup vs baseline: 1.9390x; 1.5318x over previous
//
#include <hip/hip_runtime.h>
#include <stdint.h>

// ---------------------------------------------------------------------------
// EditorActorCritic: embed GEMM -> input-proj GEMM -> clustered LSTM scan ->
// actor/critic head GEMMs.  fp32/bf16 input dtype detected at runtime;
// compute is bf16 MFMA, fp32 accumulate.
// LSTM h-exchange: relaxed tag-in-word protocol ({tag:16,h:16} per 4B word,
// parity double-buffer).  Round-6 change: COALESCED poll sweeps (lane l loads
// word i*64+l -> 64x fewer memory transactions than the m-strided pattern of
// rounds 3/5, which was transaction-bound at ~4096 scattered txn/WG/sweep),
// then LDS redistribution to MFMA A-fragment layout.
// ---------------------------------------------------------------------------

typedef short v8s __attribute__((ext_vector_type(8)));   // 8 x bf16 bits (MFMA A/B frag)
typedef float v4f __attribute__((ext_vector_type(4)));   // MFMA C/D frag

#define DEV static __device__ __forceinline__
#define DT_THRESH 4096

DEV float b2f(unsigned short h) {
    union { unsigned int u; float f; } v; v.u = ((unsigned int)h) << 16; return v.f;
}
DEV unsigned short f2b(float f) {
    union { float f; unsigned int u; } v; v.f = f;
    unsigned int u = v.u;
    return (unsigned short)((u + 0x7fffu + ((u >> 16) & 1u)) >> 16);
}
DEV float sigf(float x) {
    x = fminf(fmaxf(x, -30.f), 30.f);
    return 1.f / (1.f + __expf(-x));
}
DEV float tanh_(float x) {
    x = fminf(fmaxf(x, -15.f), 15.f);
    float e = __expf(-2.f * x);
    return (1.f - e) / (1.f + e);
}

// ---------------------------------------------------------------------------
// K0a: dones decode (robust int32/bf16/byte) + zero the dtype-flag counter.
// ---------------------------------------------------------------------------
__global__ __launch_bounds__(1024) void dones_k(const void* __restrict__ raw,
                                                int* __restrict__ dst,
                                                int* __restrict__ dt) {
    __shared__ int bad_int, bad_bf;
    int tid = threadIdx.x;
    if (tid == 0) { bad_int = 0; bad_bf = 0; dt[0] = 0; }
    __syncthreads();
    const unsigned int* w = (const unsigned int*)raw;
    int li = 0, lb = 0;
    for (int i = tid; i < 32768; i += 1024) {
        unsigned int v = w[i];
        if (v > 1u) li = 1;
        unsigned int h0 = v & 0xffffu, h1 = v >> 16;
        if ((h0 != 0u && h0 != 0x3f80u) || (h1 != 0u && h1 != 0x3f80u)) lb = 1;
    }
    if (li) atomicOr(&bad_int, 1);
    if (lb) atomicOr(&bad_bf, 1);
    __syncthreads();
    int mode = (!bad_int) ? 0 : ((!bad_bf) ? 1 : 2);
    for (int e = tid; e < 131072; e += 1024) {
        int v;
        if (mode == 0)      v = (((const int*)raw)[e] != 0);
        else if (mode == 1) v = (((const unsigned short*)raw)[e] != 0);
        else                v = (((const unsigned char*)raw)[e] != 0);
        dst[e] = v;
    }
}

// ---------------------------------------------------------------------------
// K0b: float-dtype detect.
// ---------------------------------------------------------------------------
__global__ __launch_bounds__(256) void detect_k(const unsigned short* __restrict__ xr,
                                                int* __restrict__ dt) {
    int tid = blockIdx.x * 256 + threadIdx.x;   // 16384 threads
    int cnt = 0;
    for (int i = tid; i < (1 << 24); i += 16384) {
        unsigned int e = (xr[i] >> 7) & 0xffu;
        cnt += (e >= 140u);
    }
    for (int o = 32; o; o >>= 1) cnt += __shfl_down(cnt, o);
    if ((threadIdx.x & 63) == 0 && cnt) atomicAdd(dt, cnt);
}

// ---------------------------------------------------------------------------
// K0c: x -> bf16 canonical copy.
// ---------------------------------------------------------------------------
__global__ __launch_bounds__(256) void cvt_x_k(const void* __restrict__ xr,
                                               unsigned short* __restrict__ xb,
                                               const int* __restrict__ dt) {
    int fp32i = dt[0] > DT_THRESH;
    long i4 = (long)blockIdx.x * 256 + threadIdx.x;
    if (fp32i) {
        float4 v = ((const float4*)xr)[i4];
        uint2 p;
        p.x = (unsigned int)f2b(v.x) | ((unsigned int)f2b(v.y) << 16);
        p.y = (unsigned int)f2b(v.z) | ((unsigned int)f2b(v.w) << 16);
        ((uint2*)xb)[i4] = p;
    } else {
        ((uint2*)xb)[i4] = ((const uint2*)xr)[i4];
    }
}

// ---------------------------------------------------------------------------
// K0d: transpose (and dtype-convert) weight matrices W[R][C] -> WT[C][R] bf16.
// ---------------------------------------------------------------------------
struct TransArgs {
    const void* src[9];
    unsigned short* dst[9];
    int R[9];
    int C[9];
    int prefix[10];
    int total;
};

__global__ __launch_bounds__(256) void trans_kernel(TransArgs a, const int* __restrict__ dt) {
    int fp32i = dt[0] > DT_THRESH;
    int id = blockIdx.x * 256 + threadIdx.x;
    if (id >= a.total) return;
    int m = 0;
#pragma unroll
    for (int k = 0; k < 9; k++)
        if (id >= a.prefix[k + 1]) m = k + 1;
    int e = id - a.prefix[m];
    int C = a.C[m];
    int r = e / C, c = e % C;
    unsigned short v;
    if (fp32i) v = f2b(((const float*)a.src[m])[e]);
    else       v = ((const unsigned short*)a.src[m])[e];
    a.dst[m][c * a.R[m] + r] = v;
}

// ---------------------------------------------------------------------------
// Generic bf16 GEMM (verified since round 3).
// ---------------------------------------------------------------------------
template <int TN, int ACT, int OM>
__global__ __launch_bounds__(256) void gemm_k(const unsigned short* __restrict__ A,
                                              const unsigned short* __restrict__ BT,
                                              const unsigned short* __restrict__ bias,
                                              void* __restrict__ Cout, long coff,
                                              const int* __restrict__ dtf,
                                              int N, int K) {
    __shared__ unsigned short As[128][40];
    __shared__ unsigned short Bs[TN][40];
    const int tid = threadIdx.x;
    const int l = tid & 63, w = tid >> 6;
    const long m0 = (long)blockIdx.x * 128;
    const int n0 = blockIdx.y * TN;
    constexpr int NRT = (TN == 128) ? 4 : 2;
    constexpr int NCT = (TN == 128) ? 4 : 1;
    int fp32o = (OM == 1) ? (dtf[0] > DT_THRESH) : 0;

    v4f acc[NRT][NCT];
    for (int i = 0; i < NRT; i++)
        for (int j = 0; j < NCT; j++) acc[i][j] = v4f{0.f, 0.f, 0.f, 0.f};

    for (int kc = 0; kc < K; kc += 32) {
        {
            int row = tid >> 1, part = tid & 1;
            const uint4* src = (const uint4*)(A + (m0 + row) * K + kc + part * 16);
            uint4 v0 = src[0], v1 = src[1];
            *(uint4*)&As[row][part * 16] = v0;
            *(uint4*)&As[row][part * 16 + 8] = v1;
        }
        if (TN == 128) {
            int row = tid >> 1, part = tid & 1;
            const uint4* src = (const uint4*)(BT + (long)(n0 + row) * K + kc + part * 16);
            uint4 v0 = src[0], v1 = src[1];
            *(uint4*)&Bs[row][part * 16] = v0;
            *(uint4*)&Bs[row][part * 16 + 8] = v1;
        } else if (tid < 32) {
            int row = tid >> 1, part = tid & 1;
            const uint4* src = (const uint4*)(BT + (long)(n0 + row) * K + kc + part * 16);
            uint4 v0 = src[0], v1 = src[1];
            *(uint4*)&Bs[row][part * 16] = v0;
            *(uint4*)&Bs[row][part * 16 + 8] = v1;
        }
        __syncthreads();

        v8s af[NRT], bf[NCT];
#pragma unroll
        for (int i = 0; i < NRT; i++) {
            int rt = (TN == 128) ? ((w >> 1) * 4 + i) : (w * 2 + i);
            af[i] = *(const v8s*)&As[rt * 16 + (l & 15)][(l >> 4) * 8];
        }
#pragma unroll
        for (int j = 0; j < NCT; j++) {
            int ct = (TN == 128) ? ((w & 1) * 4 + j) : 0;
            bf[j] = *(const v8s*)&Bs[ct * 16 + (l & 15)][(l >> 4) * 8];
        }
#pragma unroll
        for (int i = 0; i < NRT; i++)
#pragma unroll
            for (int j = 0; j < NCT; j++)
                acc[i][j] = __builtin_amdgcn_mfma_f32_16x16x32_bf16(af[i], bf[j], acc[i][j], 0, 0, 0);
        __syncthreads();
    }

#pragma unroll
    for (int j = 0; j < NCT; j++) {
        int ct = (TN == 128) ? ((w & 1) * 4 + j) : 0;
        int col = ct * 16 + (l & 15);
        float bv = b2f(bias[n0 + col]);
#pragma unroll
        for (int i = 0; i < NRT; i++) {
            int rt = (TN == 128) ? ((w >> 1) * 4 + i) : (w * 2 + i);
#pragma unroll
            for (int q = 0; q < 4; q++) {
                long row = m0 + rt * 16 + (l >> 4) * 4 + q;
                float v = acc[i][j][q] + bv;
                if (ACT == 1) v = fmaxf(v, 0.f);
                if (ACT == 2) v = tanh_(v);
                long idx = coff + row * (long)N + n0 + col;
                if (OM == 1 && fp32o) ((float*)Cout)[idx] = v;
                else ((unsigned short*)Cout)[idx] = f2b(v);
            }
        }
    }
}

// ---------------------------------------------------------------------------
// K2: LSTM scan.  16 clusters x 16 WGs (1 wave).  Relaxed tag-in-word
// exchange, parity double-buffer.  Poll: COALESCED sweeps (lane l loads word
// i*64+l, 64 x 256B transactions), ballot tag check, then scatter stripped
// h bits to LDS (hlds) and read MFMA A-frags via ds_read_b128.
// cluster = blockIdx & 15: cluster peers likely share an XCD (latency
// heuristic only; correctness is dispatch-independent).
// ---------------------------------------------------------------------------
#define HB_WORDS 65536

__global__ __launch_bounds__(64) void lstm_k(const unsigned short* __restrict__ xz,   // [512*256][1024]
                                             const int* __restrict__ dones,           // [512][256] decoded
                                             const void* __restrict__ h0c,
                                             const void* __restrict__ h0h,
                                             const unsigned short* __restrict__ WhT,  // [1024][256]
                                             unsigned int* __restrict__ hb,           // [2][65536]
                                             unsigned short* __restrict__ hs,         // [512*256][256] (bf16)
                                             void* __restrict__ outv,
                                             const int* __restrict__ dtf) {
    __shared__ unsigned short Whs[64][264];   // [g*16+n][k]
    __shared__ unsigned short hlds[16][264];  // [row][k] current-h tile (+8 pad)
    __shared__ unsigned short xzs[16][72];    // [row][g*16+n]
    __shared__ int dns[16];

    const int l = threadIdx.x;      // one wave
    const int cluster = blockIdx.x & 15;
    const int rank = blockIdx.x >> 4;
    const int bt = cluster * 16;
    const int m = l & 15;
    const int qq = l >> 4;
    const int hc = rank * 16 + m;
    const int fp32o = dtf[0] > DT_THRESH;
    const int meven = ((m & 1) == 0);

    // Wh slice -> LDS (once)
    {
        int zc = qq * 256 + rank * 16 + m;
        const unsigned short* srcp = WhT + (long)zc * 256;
#pragma unroll
        for (int k8 = 0; k8 < 32; k8++) {
            uint4 v = *(const uint4*)(srcp + k8 * 8);
            *(uint4*)&Whs[l][k8 * 8] = v;
        }
    }
    __syncthreads();

    // init: c from h0c; publish h0h into parity-0 words with tag 0
    float c[4], hn[4];
#pragma unroll
    for (int q = 0; q < 4; q++) {
        int row = qq * 4 + q;
        long idx = (long)(bt + row) * 256 + hc;
        c[q] = fp32o ? ((const float*)h0c)[idx] : b2f(((const unsigned short*)h0c)[idx]);
        float h0 = fp32o ? ((const float*)h0h)[idx] : b2f(((const unsigned short*)h0h)[idx]);
        unsigned short hbits = f2b(h0);
        __hip_atomic_store(&hb[(size_t)cluster * 4096 + row * 256 + hc],
                           (unsigned int)hbits,   // tag 0 in high bits
                           __ATOMIC_RELAXED, __HIP_MEMORY_SCOPE_AGENT);
        hn[q] = 0.f;
    }

    int dead = 0;
    unsigned int va[64];

    for (int t = 0; t < 512; t++) {
        const unsigned int tag = (unsigned int)t;
        const unsigned int* rb = hb + (size_t)(t & 1) * HB_WORDS + (size_t)cluster * 4096;

        // stage dones + xz slice for this step (overlaps the poll sweeps)
        if (l < 16) dns[l] = dones[t * 256 + bt + l];
        {
            int row = l >> 2, g = l & 3;
            const uint4* src = (const uint4*)(xz + ((long)(t * 256 + bt + row)) * 1024 + g * 256 + rank * 16);
            uint4 v0 = src[0], v1 = src[1];
            *(uint4*)&xzs[row][g * 16] = v0;
            *(uint4*)&xzs[row][g * 16 + 8] = v1;
        }

        // coalesced poll sweeps over the whole cluster tile (4096 words)
        if (!dead) {
            int guard = 0;
            while (true) {
#pragma unroll
                for (int i = 0; i < 64; i++)
                    va[i] = __hip_atomic_load(&rb[i * 64 + l],
                                              __ATOMIC_RELAXED, __HIP_MEMORY_SCOPE_AGENT);
                unsigned int okl = 1u;
#pragma unroll
                for (int i = 0; i < 64; i++) okl &= ((va[i] >> 16) == tag) ? 1u : 0u;
                if (__ballot(okl != 0u) == ~0ull) break;
                if (++guard > (1 << 13)) { dead = 1; break; }
            }
        }

        // scatter stripped h bits to LDS: word i*64+l -> row=i>>2, col=(i&3)*64+l
#pragma unroll
        for (int i = 0; i < 64; i++)
            hlds[i >> 2][(i & 3) * 64 + l] = (unsigned short)(va[i] & 0xffffu);
        __syncthreads();  // hlds/dns/xzs visible

        // MFMA: 4 gate tiles, K=256; A-frag via ds_read_b128 from hlds
        int dnA = dns[m];
        v4f acc[4];
#pragma unroll
        for (int g = 0; g < 4; g++) acc[g] = v4f{0.f, 0.f, 0.f, 0.f};
#pragma unroll
        for (int ks = 0; ks < 8; ks++) {
            v8s a = *(const v8s*)&hlds[m][ks * 32 + qq * 8];
            if (dnA) a = v8s{0, 0, 0, 0, 0, 0, 0, 0};
#pragma unroll
            for (int g = 0; g < 4; g++) {
                v8s b = *(const v8s*)&Whs[g * 16 + m][ks * 32 + qq * 8];
                acc[g] = __builtin_amdgcn_mfma_f32_16x16x32_bf16(a, b, acc[g], 0, 0, 0);
            }
        }

        // gates + state update + publish {t+1, h} + packed hs history
        unsigned int* wb = hb + (size_t)((t + 1) & 1) * HB_WORDS + (size_t)cluster * 4096;
#pragma unroll
        for (int q = 0; q < 4; q++) {
            int row = qq * 4 + q;
            float zi = acc[0][q] + b2f(xzs[row][0 + m]);
            float zf = acc[1][q] + b2f(xzs[row][16 + m]);
            float zg = acc[2][q] + b2f(xzs[row][32 + m]);
            float zo = acc[3][q] + b2f(xzs[row][48 + m]);
            float cm = dns[row] ? 0.f : c[q];
            float cn = sigf(zf) * cm + sigf(zi) * tanh_(zg);
            float h = sigf(zo) * tanh_(cn);
            c[q] = cn;
            hn[q] = h;
            unsigned short hbits = f2b(h);
            __hip_atomic_store(&wb[row * 256 + hc],
                               (((unsigned int)(t + 1)) << 16) | (unsigned int)hbits,
                               __ATOMIC_RELAXED, __HIP_MEMORY_SCOPE_AGENT);
            unsigned int pr = (unsigned int)__shfl_xor((int)hbits, 1);
            if (meven) {
                unsigned int wv = (unsigned int)hbits | (pr << 16);
                ((unsigned int*)hs)[((long)(t * 256 + bt + row)) * 128 + rank * 8 + (m >> 1)] = wv;
            }
        }
        __syncthreads();  // keep hlds WAR-safe across steps (1 wave: cheap)
    }

    // c_fin at out elems [0:65536], h_fin at [65536:131072]
#pragma unroll
    for (int q = 0; q < 4; q++) {
        int row = qq * 4 + q;
        long i1 = (long)(bt + row) * 256 + hc;
        long i2 = 65536 + i1;
        if (fp32o) {
            ((float*)outv)[i1] = c[q];
            ((float*)outv)[i2] = hn[q];
        } else {
            ((unsigned short*)outv)[i1] = f2b(c[q]);
            ((unsigned short*)outv)[i2] = f2b(hn[q]);
        }
    }
}

// ---------------------------------------------------------------------------
// value head: value[r] = v2[r] . Wc3 + bc3   (K=128, N=1)
// ---------------------------------------------------------------------------
__global__ __launch_bounds__(256) void value_k(const unsigned short* __restrict__ V2,
                                               const unsigned short* __restrict__ Wc3T,
                                               const unsigned short* __restrict__ bc3,
                                               void* __restrict__ outv,
                                               const int* __restrict__ dtf) {
    int tid = threadIdx.x;
    int l = tid & 63, w = tid >> 6;
    int fp32o = dtf[0] > DT_THRESH;
    long row = (long)blockIdx.x * 32 + w * 8 + (l >> 3);
    int sub = l & 7;
    const unsigned short* vp = V2 + row * 128 + sub * 16;
    float s = 0.f;
#pragma unroll
    for (int j = 0; j < 16; j++) s += b2f(vp[j]) * b2f(Wc3T[sub * 16 + j]);
    s += __shfl_xor(s, 1);
    s += __shfl_xor(s, 2);
    s += __shfl_xor(s, 4);
    if (sub == 0) {
        float v = s + b2f(bc3[0]);
        if (fp32o) ((float*)outv)[2228224 + row] = v;
        else ((unsigned short*)outv)[2228224 + row] = f2b(v);
    }
}

// ---------------------------------------------------------------------------
// host launcher
// ---------------------------------------------------------------------------
extern "C" void kernel_launch(void* const* d_in, const int* in_sizes, int n_in,
                              void* d_out, int out_size, void* d_ws, size_t ws_size,
                              hipStream_t stream) {
    const void* x             = d_in[0];
    const void* dones_raw     = d_in[1];
    const void* h0c           = d_in[2];
    const void* h0h           = d_in[3];
    const void* We  = d_in[4];
    const unsigned short* be  = (const unsigned short*)d_in[5];
    const void* Wi  = d_in[6];
    const void* Wh  = d_in[7];
    const unsigned short* bl  = (const unsigned short*)d_in[8];
    const void* Wa1 = d_in[9];
    const unsigned short* ba1 = (const unsigned short*)d_in[10];
    const void* Wa2 = d_in[11];
    const unsigned short* ba2 = (const unsigned short*)d_in[12];
    const void* Wa3 = d_in[13];
    const unsigned short* ba3 = (const unsigned short*)d_in[14];
    const void* Wc1 = d_in[15];
    const unsigned short* bc1 = (const unsigned short*)d_in[16];
    const void* Wc2 = d_in[17];
    const unsigned short* bc2 = (const unsigned short*)d_in[18];
    const void* Wc3 = d_in[19];
    const unsigned short* bc3 = (const unsigned short*)d_in[20];
    char* ws = (char*)d_ws;

    // workspace layout (bytes)
    unsigned short* WeT  = (unsigned short*)(ws + 0);          //   131072
    unsigned short* WiT  = (unsigned short*)(ws + 131072);     //   524288
    unsigned short* WhT  = (unsigned short*)(ws + 655360);     //   524288
    unsigned short* Wa1T = (unsigned short*)(ws + 1179648);    //    65536
    unsigned short* Wa2T = (unsigned short*)(ws + 1245184);    //    32768
    unsigned short* Wa3T = (unsigned short*)(ws + 1277952);    //     4096
    unsigned short* Wc1T = (unsigned short*)(ws + 1282048);    //    65536
    unsigned short* Wc2T = (unsigned short*)(ws + 1347584);    //    32768
    unsigned short* Wc3T = (unsigned short*)(ws + 1380352);    //      256
    int*            DT   = (int*)(ws + 1380608);               //       64
    unsigned int*   HB   = (unsigned int*)(ws + 1380672);      //   524288 (2x65536 words)
    int*            DN   = (int*)(ws + 1904960);               //   524288
    unsigned short* XB   = (unsigned short*)(ws + 2429248);    // 67108864
    unsigned short* E    = (unsigned short*)(ws + 69538112);   // 67108864
    unsigned short* XZ   = (unsigned short*)(ws + 136646976);  // 268435456
    unsigned short* HS   = (unsigned short*)(ws + 405082432);  // 67108864 -> ends 472191296
    unsigned short* H1   = XB;                                  // alias (XB dead post-E)
    unsigned short* H2   = XB + 16777216;

    TransArgs ta;
    {
        const void* srcs[9] = {We, Wi, Wh, Wa1, Wa2, Wa3, Wc1, Wc2, Wc3};
        unsigned short* dsts[9] = {WeT, WiT, WhT, Wa1T, Wa2T, Wa3T, Wc1T, Wc2T, Wc3T};
        int Rs[9] = {256, 256, 256, 256, 128, 128, 256, 128, 128};
        int Cs[9] = {256, 1024, 1024, 128, 128, 16, 128, 128, 1};
        int p = 0;
        for (int i = 0; i < 9; i++) {
            ta.src[i] = srcs[i];
            ta.dst[i] = dsts[i];
            ta.R[i] = Rs[i];
            ta.C[i] = Cs[i];
            ta.prefix[i] = p;
            p += Rs[i] * Cs[i];
        }
        ta.prefix[9] = p;
        ta.total = p;  // 690304
    }

    dones_k<<<1, 1024, 0, stream>>>(dones_raw, DN, DT);
    detect_k<<<64, 256, 0, stream>>>((const unsigned short*)x, DT);
    cvt_x_k<<<32768, 256, 0, stream>>>(x, XB, DT);
    trans_kernel<<<2697, 256, 0, stream>>>(ta, DT);

    // E = relu(x @ We + be)            [131072 x 256]
    gemm_k<128, 1, 0><<<dim3(1024, 2), 256, 0, stream>>>(XB, WeT, be, E, 0, nullptr, 256, 256);
    // XZ = E @ Wi + b_lstm             [131072 x 1024]
    gemm_k<128, 0, 0><<<dim3(1024, 8), 256, 0, stream>>>(E, WiT, bl, XZ, 0, nullptr, 1024, 256);
    // LSTM scan -> HS, c_fin, h_fin
    lstm_k<<<256, 64, 0, stream>>>(XZ, DN, h0c, h0h, WhT, HB, HS, d_out, DT);
    // actor head
    gemm_k<128, 2, 0><<<dim3(1024, 1), 256, 0, stream>>>(HS, Wa1T, ba1, H1, 0, nullptr, 128, 256);
    gemm_k<128, 2, 0><<<dim3(1024, 1), 256, 0, stream>>>(H1, Wa2T, ba2, H2, 0, nullptr, 128, 128);
    gemm_k<16, 0, 1><<<dim3(1024, 1), 256, 0, stream>>>(H2, Wa3T, ba3, d_out, 131072, DT, 16, 128);
    // critic head
    gemm_k<128, 2, 0><<<dim3(1024, 1), 256, 0, stream>>>(HS, Wc1T, bc1, H1, 0, nullptr, 128, 256);
    gemm_k<128, 2, 0><<<dim3(1024, 1), 256, 0, stream>>>(H1, Wc2T, bc2, H2, 0, nullptr, 128, 128);
    value_k<<<4096, 256, 0, stream>>>(H2, Wc3T, bc3, d_out, DT);
}